// Round 10
// baseline (3000.870 us; speedup 1.0000x reference)
//
#include <hip/hip_runtime.h>
#include <hip/hip_fp16.h>

// GNN: fc1 -> GCNConv x2 -> mean-pool -> L2norm -> fc2
// N=100000, E=1.6M, F=H=128, O=64, G=1024.
// R10: range-pinned partial aggregation, dst-tiled to T=2 passes so the
// partial buffer (8 x 50048 x 256B = 102.5MB) fits ws. Range r (12.5k src,
// 3.2MB fp16 rows) pinned to XCD r via bid&7 -> gather reuse 8/line/pass,
// miss ~12% (vs 50% unpinned; R4 proved residency). Block = (dst-chunk-128,
// r): fp32 LDS slab accumulate, fp16 partial write. k_reduce sums 8 partials
// + self + bias/PReLU (+pool). Fallback to R8 pull if ws too small.

#define CHK 1024  // scan chunk size
#define LDSTRIDE 130
typedef unsigned int u32;
using f16 = _Float16;
using f16x8 = __attribute__((ext_vector_type(8))) _Float16;
using f32x4 = __attribute__((ext_vector_type(4))) float;

// ---------------- degree / normalization ----------------

__global__ __launch_bounds__(256) void k_hist_deg(const int* __restrict__ dst,
                                                  const float* __restrict__ w,
                                                  float* __restrict__ degf, int E) {
  int e = blockIdx.x * 256 + threadIdx.x;
  if (e < E) atomicAdd(&degf[dst[e]], w[e]);
}

__global__ __launch_bounds__(256) void k_dis(const float* __restrict__ degf,
                                             float* __restrict__ dis,
                                             float* __restrict__ inv, int N) {
  int n = blockIdx.x * 256 + threadIdx.x;
  if (n < N) {
    float deg = degf[n] + 1.0f;  // self-loop weight 1
    dis[n] = rsqrtf(deg);
    inv[n] = 1.0f / deg;
  }
}

// ---------------- histogram + scan ----------------

__global__ __launch_bounds__(256) void k_hist_cnt_bucket(const int* __restrict__ src,
                                                         const int* __restrict__ dst,
                                                         int* __restrict__ cnt, int E,
                                                         int RANGE) {
  int e = blockIdx.x * 256 + threadIdx.x;
  if (e < E) {
    int bucket = (dst[e] >> 7) * 8 + (src[e] / RANGE);
    atomicAdd(&cnt[bucket], 1);
  }
}

__global__ __launch_bounds__(256) void k_hist_cnt_dst(const int* __restrict__ dst,
                                                      int* __restrict__ cnt, int E) {
  int e = blockIdx.x * 256 + threadIdx.x;
  if (e < E) atomicAdd(&cnt[dst[e]], 1);
}

__global__ __launch_bounds__(256) void k_scan_reduce(const int* __restrict__ cnt,
                                                     int* __restrict__ chunkSum, int N) {
  __shared__ int sd[256];
  int b = blockIdx.x, t = threadIdx.x;
  int base = b * CHK + t * 4;
  int s = 0;
#pragma unroll
  for (int i = 0; i < 4; i++)
    if (base + i < N) s += cnt[base + i];
  sd[t] = s;
  __syncthreads();
  for (int off = 128; off; off >>= 1) {
    if (t < off) sd[t] += sd[t + off];
    __syncthreads();
  }
  if (t == 0) chunkSum[b] = sd[0];
}

__global__ void k_scan_chunks(const int* __restrict__ chunkSum,
                              int* __restrict__ chunkOff, int NC) {
  if (threadIdx.x == 0 && blockIdx.x == 0) {
    int s = 0;
    for (int i = 0; i < NC; i++) {
      chunkOff[i] = s;
      s += chunkSum[i];
    }
  }
}

__global__ __launch_bounds__(256) void k_scan_final(const int* __restrict__ cnt,
                                                    const int* __restrict__ chunkOff,
                                                    int* __restrict__ rowptr,
                                                    int* __restrict__ cursor, int N, int E) {
  __shared__ int sd[256];
  int b = blockIdx.x, t = threadIdx.x;
  int base = b * CHK + t * 4;
  int v[4], loc[4];
#pragma unroll
  for (int i = 0; i < 4; i++) v[i] = (base + i < N) ? cnt[base + i] : 0;
  loc[0] = 0;
  loc[1] = v[0];
  loc[2] = v[0] + v[1];
  loc[3] = v[0] + v[1] + v[2];
  int tot = loc[3] + v[3];
  sd[t] = tot;
  __syncthreads();
  for (int off = 1; off < 256; off <<= 1) {
    int xv = (t >= off) ? sd[t - off] : 0;
    __syncthreads();
    sd[t] += xv;
    __syncthreads();
  }
  int tbase = (t ? sd[t - 1] : 0) + chunkOff[b];
#pragma unroll
  for (int i = 0; i < 4; i++) {
    if (base + i < N) {
      int r = tbase + loc[i];
      rowptr[base + i] = r;
      cursor[base + i] = r;
    }
  }
  if (b == 0 && t == 0) rowptr[N] = E;
}

// ---------------- edge scatter ----------------

// bucket = chunk*8 + range; record = (src | dlocal<<17, coef bits)
__global__ __launch_bounds__(256) void k_scatter_b(const int* __restrict__ src,
                                                   const int* __restrict__ dst,
                                                   const float* __restrict__ w,
                                                   const float* __restrict__ dis,
                                                   int* __restrict__ cursor,
                                                   int2* __restrict__ recs, int E,
                                                   int RANGE) {
  int e = blockIdx.x * 256 + threadIdx.x;
  if (e < E) {
    int s = src[e], d = dst[e];
    float c = w[e] * dis[s] * dis[d];
    int bucket = (d >> 7) * 8 + (s / RANGE);
    int p = atomicAdd(&cursor[bucket], 1);
    int2 v;
    v.x = s | ((d & 127) << 17);
    v.y = __float_as_int(c);
    recs[p] = v;
  }
}

// Fallback: dst-CSR record = (src, coef bits)
__global__ __launch_bounds__(256) void k_scatter_d(const int* __restrict__ src,
                                                   const int* __restrict__ dst,
                                                   const float* __restrict__ w,
                                                   const float* __restrict__ dis,
                                                   int* __restrict__ cursor,
                                                   int2* __restrict__ csr, int E) {
  int e = blockIdx.x * 256 + threadIdx.x;
  if (e < E) {
    int s = src[e], d = dst[e];
    float c = w[e] * dis[s] * dis[d];
    int p = atomicAdd(&cursor[d], 1);
    int2 v;
    v.x = s;
    v.y = __float_as_int(c);
    csr[p] = v;
  }
}

// ---------------- MFMA GEMM (unchanged from R5) ----------------

__global__ __launch_bounds__(256) void k_prep_bfrag(const float* __restrict__ W,
                                                    f16x8* __restrict__ Bf) {
  int t = blockIdx.x * 256 + threadIdx.x;  // 0..2047
  int combo = t >> 6;                      // kc*8+ct
  int l = t & 63;
  int o = (combo & 7) * 16 + (l & 15);
  int k0 = (combo >> 3) * 32 + (l >> 4) * 8;
  f16x8 b;
#pragma unroll
  for (int i = 0; i < 8; i++) b[i] = (f16)W[o * 128 + k0 + i];
  Bf[combo * 64 + l] = b;
}

template <bool FP32_IN, bool BIAS>
__global__ __launch_bounds__(256) void k_gemm_mfma(const f16* __restrict__ Ah,
                                                   const float* __restrict__ Af,
                                                   const f16x8* __restrict__ Bf,
                                                   f16* __restrict__ out,
                                                   const float* __restrict__ bias,
                                                   const float* __restrict__ slope,
                                                   int N) {
  __shared__ f16 ls[64 * 128];
  int t = threadIdx.x;
  int w = t >> 6, l = t & 63;
  int l15 = l & 15, kgrp = l >> 4;
  int nodeBase = blockIdx.x * 64 + w * 16;
  f32x4 acc[8];
#pragma unroll
  for (int ct = 0; ct < 8; ct++)
#pragma unroll
    for (int j = 0; j < 4; j++) acc[ct][j] = 0.f;

  int arow = nodeBase + l15;
  if (arow >= N) arow = N - 1;  // clamp: duplicate read, store is guarded
#pragma unroll
  for (int kc = 0; kc < 4; kc++) {
    f16x8 a;
    if (FP32_IN) {
      const float4* p0 = (const float4*)(Af + (size_t)arow * 128 + kc * 32 + kgrp * 8);
      float4 x0 = p0[0], x1 = p0[1];
      a[0] = (f16)x0.x; a[1] = (f16)x0.y; a[2] = (f16)x0.z; a[3] = (f16)x0.w;
      a[4] = (f16)x1.x; a[5] = (f16)x1.y; a[6] = (f16)x1.z; a[7] = (f16)x1.w;
    } else {
      a = *(const f16x8*)(Ah + (size_t)arow * 128 + kc * 32 + kgrp * 8);
    }
#pragma unroll
    for (int ct = 0; ct < 8; ct++) {
      f16x8 b = Bf[(kc * 8 + ct) * 64 + l];
      acc[ct] = __builtin_amdgcn_mfma_f32_16x16x32_f16(a, b, acc[ct], 0, 0, 0);
    }
  }
  // C/D layout: col=l&15, row=(l>>4)*4+j  [HW-verified m89].
  float sl = BIAS ? *slope : 0.f;
  f16* slab = ls + w * 16 * 128;
#pragma unroll
  for (int ct = 0; ct < 8; ct++) {
    float bv = BIAS ? bias[ct * 16 + l15] : 0.f;
#pragma unroll
    for (int j = 0; j < 4; j++) {
      float v = acc[ct][j];
      if (BIAS) {
        v += bv;
        v = v >= 0.f ? v : sl * v;
      }
      slab[(kgrp * 4 + j) * 128 + ct * 16 + l15] = (f16)v;
    }
  }
  __syncthreads();
  {
    int r = l >> 2;
    int gnode = nodeBase + r;
    if (gnode < N) {
      const uint4* srcp = (const uint4*)(slab + r * 128);
      uint4* dstp = (uint4*)(out + (size_t)gnode * 128);
#pragma unroll
      for (int i = 0; i < 4; i++) {
        int chunk = (l & 3) + i * 4;
        dstp[chunk] = srcp[chunk];
      }
    }
  }
}

// ---------------- range-pinned LDS aggregation (pass-tiled) ----------------

// Block bid: chunk = chunk0 + (bid>>3), r = bid&7 (XCD-pinned). Processes
// bucket (chunk*8+r): gathers hW rows (range r only, 3.2MB -> L2) into a
// 128x130 fp32 LDS slab via ds_add; writes fp16 partial
// P[(r*HCN + node-passNode0)*64 + ...].
__global__ __launch_bounds__(256, 2) void k_agg_lds(const __half2* __restrict__ hW,
                                                    const int* __restrict__ rowptr,
                                                    const int2* __restrict__ recs,
                                                    __half2* __restrict__ P,
                                                    int chunk0, int HCN, int N) {
  __shared__ float lds[128 * LDSTRIDE];
  int t = threadIdx.x;
  int bid = blockIdx.x;
  int r = bid & 7;
  int chunk = chunk0 + (bid >> 3);
  int chunkBase = chunk * 128;
  int passNode0 = chunk0 * 128;
  for (int i = t; i < 128 * LDSTRIDE / 4; i += 256) ((float4*)lds)[i] = float4{0, 0, 0, 0};
  __syncthreads();

  int w = t >> 6, l = t & 63;
  int bucket = chunk * 8 + r;
  int b0 = rowptr[bucket], b1 = rowptr[bucket + 1];
  for (int g0 = b0 + w * 64; g0 < b1; g0 += 256) {
    int idx = g0 + l;
    int xv = 0;
    float cv = 0.f;
    if (idx < b1) {
      int2 e = recs[idx];
      xv = e.x;
      cv = __int_as_float(e.y);
    }
    int m = min(64, b1 - g0);
    for (int k = 0; k < m; k += 16) {
      __half2 v[16];
      float cc[16];
      int dd[16];
#pragma unroll
      for (int i = 0; i < 16; i++) {
        int x = __shfl(xv, k + i);
        cc[i] = __shfl(cv, k + i);
        int s = x & 0x1FFFF;
        dd[i] = (x >> 17) & 127;
        v[i] = hW[(size_t)s * 64 + l];  // OOB lanes: x=0,c=0 -> adds 0 to row 0
      }
#pragma unroll
      for (int i = 0; i < 16; i++) {
        float2 f = __half22float2(v[i]);
        float* lp = lds + dd[i] * LDSTRIDE + 2 * l;
        atomicAdd(lp, f.x * cc[i]);
        atomicAdd(lp + 1, f.y * cc[i]);
      }
    }
  }
  __syncthreads();
  // fp16 partial write: 128 rows x 16 uint4
  for (int i = 0; i < 8; i++) {
    int u4 = t + 256 * i;
    int row = u4 >> 4, pos = u4 & 15;
    int node = chunkBase + row;
    if (node < N) {
      const float* rp = lds + row * LDSTRIDE + pos * 8;
      __half2 h[4];
#pragma unroll
      for (int j = 0; j < 4; j++) h[j] = __float22half2_rn(make_float2(rp[2 * j], rp[2 * j + 1]));
      *(uint4*)(P + ((size_t)r * HCN + (node - passNode0)) * 64 + pos * 4) = *(uint4*)h;
    }
  }
}

// Combine 8 partials + self + bias/PReLU for the pass's nodes.
template <bool POOL>
__global__ __launch_bounds__(256) void k_reduce(const __half2* __restrict__ P,
                                                const __half2* __restrict__ hW,
                                                const float* __restrict__ inv,
                                                const float* __restrict__ bias,
                                                const float* __restrict__ slope,
                                                const int* __restrict__ batch,
                                                __half2* __restrict__ outh,
                                                float* __restrict__ pool,
                                                float* __restrict__ cntg,
                                                int passNode0, int HCN, int N) {
  int i = blockIdx.x * 256 + threadIdx.x;  // over HCN*64 half2 slots
  if (i >= HCN * 64) return;
  int fp = i & 63;
  int pn = i >> 6;
  int node = passNode0 + pn;
  if (node >= N) return;
  float iv = inv[node];
  float2 f = __half22float2(hW[(size_t)node * 64 + fp]);
  float2 acc = make_float2(f.x * iv, f.y * iv);
#pragma unroll
  for (int r = 0; r < 8; r++) {
    float2 p = __half22float2(P[((size_t)r * HCN + pn) * 64 + fp]);
    acc.x += p.x;
    acc.y += p.y;
  }
  float a = *slope;
  float2 b = *(const float2*)&bias[fp * 2];
  acc.x += b.x;
  acc.y += b.y;
  acc.x = acc.x >= 0.f ? acc.x : a * acc.x;
  acc.y = acc.y >= 0.f ? acc.y : a * acc.y;
  if (POOL) {
    int g = batch[node];
    atomicAdd(&pool[(size_t)g * 128 + fp * 2], acc.x);
    atomicAdd(&pool[(size_t)g * 128 + fp * 2 + 1], acc.y);
    if (fp == 0) atomicAdd(&cntg[g], 1.0f);
  } else {
    outh[(size_t)node * 64 + fp] = __float22half2_rn(acc);
  }
}

// ---------------- FALLBACK: R8 pull aggregation ----------------

template <bool POOL>
__global__ __launch_bounds__(256) void k_agg_h(const __half2* __restrict__ hW,
                                               const int* __restrict__ rowptr,
                                               const int2* __restrict__ csr,
                                               const float* __restrict__ inv,
                                               const float* __restrict__ bias,
                                               const float* __restrict__ slope,
                                               const int* __restrict__ batch,
                                               __half2* __restrict__ outh,
                                               float* __restrict__ pool,
                                               float* __restrict__ cntg, int N) {
  int wid = (blockIdx.x * 256 + threadIdx.x) >> 6;
  if (wid >= N) return;
  int l = threadIdx.x & 63;
  int r0 = rowptr[wid], r1 = rowptr[wid + 1];
  float2 acc;
  {
    float2 f = __half22float2(hW[(size_t)wid * 64 + l]);
    float iv = inv[wid];
    acc.x = f.x * iv;
    acc.y = f.y * iv;
  }
  for (int base = r0; base < r1; base += 64) {
    int idx = base + l;
    int sl = 0;
    float cl = 0.f;
    if (idx < r1) {
      int2 e = csr[idx];
      sl = e.x;
      cl = __int_as_float(e.y);
    }
    int m = min(64, r1 - base);
    for (int k = 0; k < m; k += 16) {
      __half2 v[16];
      float c[16];
#pragma unroll
      for (int i = 0; i < 16; i++) {
        int s = __shfl(sl, k + i);
        c[i] = __shfl(cl, k + i);
        v[i] = hW[(size_t)s * 64 + l];
      }
#pragma unroll
      for (int i = 0; i < 16; i++) {
        float2 f = __half22float2(v[i]);
        acc.x += f.x * c[i];
        acc.y += f.y * c[i];
      }
    }
  }
  float a = *slope;
  float2 b = *(const float2*)&bias[l * 2];
  acc.x += b.x;
  acc.y += b.y;
  acc.x = acc.x >= 0.f ? acc.x : a * acc.x;
  acc.y = acc.y >= 0.f ? acc.y : a * acc.y;
  if (POOL) {
    int g = batch[wid];
    atomicAdd(&pool[(size_t)g * 128 + l * 2], acc.x);
    atomicAdd(&pool[(size_t)g * 128 + l * 2 + 1], acc.y);
    if (l == 0) atomicAdd(&cntg[g], 1.0f);
  } else {
    outh[(size_t)wid * 64 + l] = __float22half2_rn(acc);
  }
}

// ---------------- final: mean, L2norm, fc2 ----------------

__global__ __launch_bounds__(64) void k_final(const float* __restrict__ pool,
                                              const float* __restrict__ cntg,
                                              const float* __restrict__ fc2w,
                                              const float* __restrict__ fc2b,
                                              float* __restrict__ out) {
  __shared__ float hg[128];
  int g = blockIdx.x, l = threadIdx.x;
  float cnt = cntg[g];
  float ic = 1.0f / fmaxf(cnt, 1.0f);
  float2 v = *(const float2*)&pool[(size_t)g * 128 + l * 2];
  v.x *= ic;
  v.y *= ic;
  float ss = v.x * v.x + v.y * v.y;
#pragma unroll
  for (int off = 1; off < 64; off <<= 1) ss += __shfl_xor(ss, off);
  float nrm = sqrtf(ss);
  float sc = 1.0f / fmaxf(nrm, 1e-12f);
  hg[l * 2] = v.x * sc;
  hg[l * 2 + 1] = v.y * sc;
  __syncthreads();
  float acc = fc2b[l];
#pragma unroll 4
  for (int k = 0; k < 128; k++) acc += hg[k] * fc2w[l * 128 + k];
  out[(size_t)g * 64 + l] = acc;
}

extern "C" void kernel_launch(void* const* d_in, const int* in_sizes, int n_in,
                              void* d_out, int out_size, void* d_ws, size_t ws_size,
                              hipStream_t stream) {
  const float* x = (const float*)d_in[0];
  const int* ei = (const int*)d_in[1];
  const float* ew = (const float*)d_in[2];
  const int* batch = (const int*)d_in[3];
  const float* fc1_w = (const float*)d_in[4];
  const float* fc1_b = (const float*)d_in[5];
  const float* gc1_w = (const float*)d_in[6];
  const float* gc1_b = (const float*)d_in[7];
  const float* gc2_w = (const float*)d_in[8];
  const float* gc2_b = (const float*)d_in[9];
  const float* fc2_w = (const float*)d_in[10];
  const float* fc2_b = (const float*)d_in[11];
  const float* a_fc1 = (const float*)d_in[12];
  const float* a_gc1 = (const float*)d_in[13];
  const float* a_gc2 = (const float*)d_in[14];

  int N = in_sizes[0] / 128;
  int E = in_sizes[2];
  int G = out_size / 64;
  const int* src = ei;
  const int* dst = ei + E;

  int RANGE = (N + 7) / 8;          // src nodes per range
  int NCHUNK = (N + 127) >> 7;      // dst chunks of 128
  int NB = NCHUNK * 8;              // buckets
  int NBIG = N > NB ? N : NB;
  int HC = (NCHUNK + 1) / 2;        // chunks per pass (T=2)
  int HCN = HC * 128;               // nodes per pass (padded)

  char* p = (char*)d_ws;
  auto carve = [&](size_t bytes) -> char* {
    char* r = p;
    p += (bytes + 255) & ~(size_t)255;
    return r;
  };
  f16* bufA = (f16*)carve((size_t)N * 128 * 2);       // h (fp16 rows)
  f16* bufH = (f16*)carve((size_t)N * 128 * 2);       // hW (fp16 rows)
  int2* recs = (int2*)carve((size_t)E * 8);           // edge records
  int* cnt = (int*)carve((size_t)(NBIG + 1) * 4);
  int* rowptr = (int*)carve((size_t)(NBIG + 1) * 4);
  int* cursor = (int*)carve((size_t)(NBIG + 1) * 4);
  float* degf = (float*)carve((size_t)N * 4);
  float* dis = (float*)carve((size_t)N * 4);
  float* inv = (float*)carve((size_t)N * 4);
  f16x8* Bf1 = (f16x8*)carve(2048 * 16);
  f16x8* Bf2 = (f16x8*)carve(2048 * 16);
  f16x8* Bf3 = (f16x8*)carve(2048 * 16);
  int NCmax = (NBIG + CHK - 1) / CHK;
  int* chunkSum = (int*)carve((size_t)NCmax * 4);
  int* chunkOff = (int*)carve((size_t)NCmax * 4);
  float* pool = (float*)carve((size_t)G * 128 * 4);
  float* cntg = (float*)carve((size_t)G * 4);
  __half2* P = (__half2*)carve((size_t)8 * HCN * 128 * 2);  // fp16 partials (one pass)
  bool useNew = ((size_t)(p - (char*)d_ws) <= ws_size);

  hipMemsetAsync(cnt, 0, (size_t)NBIG * 4, stream);
  hipMemsetAsync(degf, 0, (size_t)N * 4, stream);
  hipMemsetAsync(pool, 0, (size_t)G * 128 * 4, stream);
  hipMemsetAsync(cntg, 0, (size_t)G * 4, stream);

  k_prep_bfrag<<<8, 256, 0, stream>>>(fc1_w, Bf1);
  k_prep_bfrag<<<8, 256, 0, stream>>>(gc1_w, Bf2);
  k_prep_bfrag<<<8, 256, 0, stream>>>(gc2_w, Bf3);

  int gE = (E + 255) / 256;
  int gN = (N + 255) / 256;
  k_hist_deg<<<gE, 256, 0, stream>>>(dst, ew, degf, E);
  k_dis<<<gN, 256, 0, stream>>>(degf, dis, inv, N);

  if (useNew) {
    int NCb = (NB + CHK - 1) / CHK;
    k_hist_cnt_bucket<<<gE, 256, 0, stream>>>(src, dst, cnt, E, RANGE);
    k_scan_reduce<<<NCb, 256, 0, stream>>>(cnt, chunkSum, NB);
    k_scan_chunks<<<1, 64, 0, stream>>>(chunkSum, chunkOff, NCb);
    k_scan_final<<<NCb, 256, 0, stream>>>(cnt, chunkOff, rowptr, cursor, NB, E);
    k_scatter_b<<<gE, 256, 0, stream>>>(src, dst, ew, dis, cursor, recs, E, RANGE);
  } else {
    int NCn = (N + CHK - 1) / CHK;
    k_hist_cnt_dst<<<gE, 256, 0, stream>>>(dst, cnt, E);
    k_scan_reduce<<<NCn, 256, 0, stream>>>(cnt, chunkSum, N);
    k_scan_chunks<<<1, 64, 0, stream>>>(chunkSum, chunkOff, NCn);
    k_scan_final<<<NCn, 256, 0, stream>>>(cnt, chunkOff, rowptr, cursor, N, E);
    k_scatter_d<<<gE, 256, 0, stream>>>(src, dst, ew, dis, cursor, recs, E);
  }

  int gGemm = (N + 63) / 64;
  int gElem = (int)(((size_t)N * 64 + 255) / 256);
  int gRed = (HCN * 64 + 255) / 256;

  // h1 = prelu(x @ fc1_w.T + fc1_b) -> bufA (fp16)
  k_gemm_mfma<true, true><<<gGemm, 256, 0, stream>>>(nullptr, x, Bf1, bufA, fc1_b, a_fc1, N);

  // conv1
  k_gemm_mfma<false, false><<<gGemm, 256, 0, stream>>>(bufA, nullptr, Bf2, bufH, nullptr, nullptr, N);
  if (useNew) {
    for (int pass = 0; pass < 2; pass++) {
      int chunk0 = pass * HC;
      int hc = NCHUNK - chunk0 < HC ? NCHUNK - chunk0 : HC;
      k_agg_lds<<<hc * 8, 256, 0, stream>>>((const __half2*)bufH, rowptr, recs, P,
                                            chunk0, HCN, N);
      k_reduce<false><<<gRed, 256, 0, stream>>>(P, (const __half2*)bufH, inv, gc1_b, a_gc1,
                                                batch, (__half2*)bufA, nullptr, cntg,
                                                chunk0 * 128, HCN, N);
    }
  } else {
    k_agg_h<false><<<gElem, 256, 0, stream>>>((const __half2*)bufH, rowptr, recs, inv, gc1_b,
                                              a_gc1, batch, (__half2*)bufA, nullptr, cntg, N);
  }

  // conv2 (+ fused pool)
  k_gemm_mfma<false, false><<<gGemm, 256, 0, stream>>>(bufA, nullptr, Bf3, bufH, nullptr, nullptr, N);
  if (useNew) {
    for (int pass = 0; pass < 2; pass++) {
      int chunk0 = pass * HC;
      int hc = NCHUNK - chunk0 < HC ? NCHUNK - chunk0 : HC;
      k_agg_lds<<<hc * 8, 256, 0, stream>>>((const __half2*)bufH, rowptr, recs, P,
                                            chunk0, HCN, N);
      k_reduce<true><<<gRed, 256, 0, stream>>>(P, (const __half2*)bufH, inv, gc2_b, a_gc2,
                                               batch, nullptr, pool, cntg,
                                               chunk0 * 128, HCN, N);
    }
  } else {
    k_agg_h<true><<<gElem, 256, 0, stream>>>((const __half2*)bufH, rowptr, recs, inv, gc2_b,
                                             a_gc2, batch, nullptr, pool, cntg, N);
  }
  k_final<<<G, 64, 0, stream>>>(pool, cntg, fc2_w, fc2_b, (float*)d_out);
}

// Round 11
// 606.968 us; speedup vs baseline: 4.9440x; 4.9440x over previous
//
#include <hip/hip_runtime.h>
#include <hip/hip_fp16.h>

// GNN: fc1 -> GCNConv x2 -> mean-pool -> L2norm -> fc2
// N=100000, E=1.6M, F=H=128, O=64, G=1024.
// R11: revert to R8 (proven 608us) with trims: fused histogram (cnt+degf in
// one E-sweep), dead code removed. Aggregation = pull, wave/node, reg-held
// CSR + shfl broadcast, 16 fp16-row gathers in flight, fp32 accum, fused
// pool atomics. MFMA GEMMs. Evidence ledger: random-gather service rate
// ~1.4TB/s of 64B lines is the ceiling (5 kernel shapes converge); blocking
// variants (XCD-pin, LDS slab, push atomics) all net-negative.

#define CHK 1024  // scan chunk size
typedef unsigned int u32;
using f16 = _Float16;
using f16x8 = __attribute__((ext_vector_type(8))) _Float16;
using f32x4 = __attribute__((ext_vector_type(4))) float;

// Fused: edge count histogram + weighted in-degree, one pass.
__global__ __launch_bounds__(256) void k_hist(const int* __restrict__ dst,
                                              const float* __restrict__ w,
                                              int* __restrict__ cnt,
                                              float* __restrict__ degf, int E) {
  int e = blockIdx.x * 256 + threadIdx.x;
  if (e < E) {
    int d = dst[e];
    atomicAdd(&cnt[d], 1);
    atomicAdd(&degf[d], w[e]);
  }
}

__global__ __launch_bounds__(256) void k_dis(const float* __restrict__ degf,
                                             float* __restrict__ dis,
                                             float* __restrict__ inv, int N) {
  int n = blockIdx.x * 256 + threadIdx.x;
  if (n < N) {
    float deg = degf[n] + 1.0f;  // self-loop weight 1
    dis[n] = rsqrtf(deg);
    inv[n] = 1.0f / deg;
  }
}

__global__ __launch_bounds__(256) void k_scan_reduce(const int* __restrict__ cnt,
                                                     int* __restrict__ chunkSum, int N) {
  __shared__ int sd[256];
  int b = blockIdx.x, t = threadIdx.x;
  int base = b * CHK + t * 4;
  int s = 0;
#pragma unroll
  for (int i = 0; i < 4; i++)
    if (base + i < N) s += cnt[base + i];
  sd[t] = s;
  __syncthreads();
  for (int off = 128; off; off >>= 1) {
    if (t < off) sd[t] += sd[t + off];
    __syncthreads();
  }
  if (t == 0) chunkSum[b] = sd[0];
}

__global__ void k_scan_chunks(const int* __restrict__ chunkSum,
                              int* __restrict__ chunkOff, int NC) {
  if (threadIdx.x == 0 && blockIdx.x == 0) {
    int s = 0;
    for (int i = 0; i < NC; i++) {
      chunkOff[i] = s;
      s += chunkSum[i];
    }
  }
}

__global__ __launch_bounds__(256) void k_scan_final(const int* __restrict__ cnt,
                                                    const int* __restrict__ chunkOff,
                                                    int* __restrict__ rowptr,
                                                    int* __restrict__ cursor, int N, int E) {
  __shared__ int sd[256];
  int b = blockIdx.x, t = threadIdx.x;
  int base = b * CHK + t * 4;
  int v[4], loc[4];
#pragma unroll
  for (int i = 0; i < 4; i++) v[i] = (base + i < N) ? cnt[base + i] : 0;
  loc[0] = 0;
  loc[1] = v[0];
  loc[2] = v[0] + v[1];
  loc[3] = v[0] + v[1] + v[2];
  int tot = loc[3] + v[3];
  sd[t] = tot;
  __syncthreads();
  for (int off = 1; off < 256; off <<= 1) {
    int xv = (t >= off) ? sd[t - off] : 0;
    __syncthreads();
    sd[t] += xv;
    __syncthreads();
  }
  int tbase = (t ? sd[t - 1] : 0) + chunkOff[b];
#pragma unroll
  for (int i = 0; i < 4; i++) {
    if (base + i < N) {
      int r = tbase + loc[i];
      rowptr[base + i] = r;
      cursor[base + i] = r;
    }
  }
  if (b == 0 && t == 0) rowptr[N] = E;
}

// CSR by dst: entry = (src, coef-bits)
__global__ __launch_bounds__(256) void k_scatter(const int* __restrict__ src,
                                                 const int* __restrict__ dst,
                                                 const float* __restrict__ w,
                                                 const float* __restrict__ dis,
                                                 int* __restrict__ cursor,
                                                 int2* __restrict__ csr, int E) {
  int e = blockIdx.x * 256 + threadIdx.x;
  if (e < E) {
    int s = src[e], d = dst[e];
    float c = w[e] * dis[s] * dis[d];
    int p = atomicAdd(&cursor[d], 1);
    int2 v;
    v.x = s;
    v.y = __float_as_int(c);
    csr[p] = v;
  }
}

// Pack W [128][128] row-major (W[o][k], fp32) into MFMA B-fragment order.
__global__ __launch_bounds__(256) void k_prep_bfrag(const float* __restrict__ W,
                                                    f16x8* __restrict__ Bf) {
  int t = blockIdx.x * 256 + threadIdx.x;  // 0..2047
  int combo = t >> 6;                      // kc*8+ct
  int l = t & 63;
  int o = (combo & 7) * 16 + (l & 15);
  int k0 = (combo >> 3) * 32 + (l >> 4) * 8;
  f16x8 b;
#pragma unroll
  for (int i = 0; i < 8; i++) b[i] = (f16)W[o * 128 + k0 + i];
  Bf[combo * 64 + l] = b;
}

// MFMA GEMM: out[n][o] = act( sum_k A[n][k]*W[o][k] (+bias) ).
template <bool FP32_IN, bool BIAS>
__global__ __launch_bounds__(256) void k_gemm_mfma(const f16* __restrict__ Ah,
                                                   const float* __restrict__ Af,
                                                   const f16x8* __restrict__ Bf,
                                                   f16* __restrict__ out,
                                                   const float* __restrict__ bias,
                                                   const float* __restrict__ slope,
                                                   int N) {
  __shared__ f16 ls[64 * 128];
  int t = threadIdx.x;
  int w = t >> 6, l = t & 63;
  int l15 = l & 15, kgrp = l >> 4;
  int nodeBase = blockIdx.x * 64 + w * 16;
  f32x4 acc[8];
#pragma unroll
  for (int ct = 0; ct < 8; ct++)
#pragma unroll
    for (int j = 0; j < 4; j++) acc[ct][j] = 0.f;

  int arow = nodeBase + l15;
  if (arow >= N) arow = N - 1;  // clamp: duplicate read, store is guarded
#pragma unroll
  for (int kc = 0; kc < 4; kc++) {
    f16x8 a;
    if (FP32_IN) {
      const float4* p0 = (const float4*)(Af + (size_t)arow * 128 + kc * 32 + kgrp * 8);
      float4 x0 = p0[0], x1 = p0[1];
      a[0] = (f16)x0.x; a[1] = (f16)x0.y; a[2] = (f16)x0.z; a[3] = (f16)x0.w;
      a[4] = (f16)x1.x; a[5] = (f16)x1.y; a[6] = (f16)x1.z; a[7] = (f16)x1.w;
    } else {
      a = *(const f16x8*)(Ah + (size_t)arow * 128 + kc * 32 + kgrp * 8);
    }
#pragma unroll
    for (int ct = 0; ct < 8; ct++) {
      f16x8 b = Bf[(kc * 8 + ct) * 64 + l];
      acc[ct] = __builtin_amdgcn_mfma_f32_16x16x32_f16(a, b, acc[ct], 0, 0, 0);
    }
  }
  // C/D layout: col=l&15, row=(l>>4)*4+j  [HW-verified m89].
  float sl = BIAS ? *slope : 0.f;
  f16* slab = ls + w * 16 * 128;
#pragma unroll
  for (int ct = 0; ct < 8; ct++) {
    float bv = BIAS ? bias[ct * 16 + l15] : 0.f;
#pragma unroll
    for (int j = 0; j < 4; j++) {
      float v = acc[ct][j];
      if (BIAS) {
        v += bv;
        v = v >= 0.f ? v : sl * v;
      }
      slab[(kgrp * 4 + j) * 128 + ct * 16 + l15] = (f16)v;
    }
  }
  __syncthreads();
  // Coalesced store: lane l -> row l>>2, chunks (l&3)+4i (16B each).
  {
    int r = l >> 2;
    int gnode = nodeBase + r;
    if (gnode < N) {
      const uint4* srcp = (const uint4*)(slab + r * 128);
      uint4* dstp = (uint4*)(out + (size_t)gnode * 128);
#pragma unroll
      for (int i = 0; i < 4; i++) {
        int chunk = (l & 3) + i * 4;
        dstp[chunk] = srcp[chunk];
      }
    }
  }
}

// Pull aggregation: wave per dst node; hW fp16 rows (64 half2); reg-held CSR
// (int2) + shfl broadcast; 16 gathers in flight; fp32 accum.
// !POOL: write fp16 row. POOL: contiguous-lane fp32 pool atomics.
template <bool POOL>
__global__ __launch_bounds__(256) void k_agg_h(const __half2* __restrict__ hW,
                                               const int* __restrict__ rowptr,
                                               const int2* __restrict__ csr,
                                               const float* __restrict__ inv,
                                               const float* __restrict__ bias,
                                               const float* __restrict__ slope,
                                               const int* __restrict__ batch,
                                               __half2* __restrict__ outh,
                                               float* __restrict__ pool,
                                               float* __restrict__ cntg, int N) {
  int wid = (blockIdx.x * 256 + threadIdx.x) >> 6;
  if (wid >= N) return;
  int l = threadIdx.x & 63;
  int r0 = rowptr[wid], r1 = rowptr[wid + 1];
  float2 acc;
  {
    float2 f = __half22float2(hW[(size_t)wid * 64 + l]);
    float iv = inv[wid];
    acc.x = f.x * iv;
    acc.y = f.y * iv;
  }
  for (int base = r0; base < r1; base += 64) {
    int idx = base + l;
    int sl = 0;
    float cl = 0.f;
    if (idx < r1) {
      int2 e = csr[idx];
      sl = e.x;
      cl = __int_as_float(e.y);
    }
    int m = min(64, r1 - base);
    for (int k = 0; k < m; k += 16) {  // k in {0,16,32,48}; k+i <= 63
      __half2 v[16];
      float c[16];
#pragma unroll
      for (int i = 0; i < 16; i++) {
        int s = __shfl(sl, k + i);
        c[i] = __shfl(cl, k + i);
        v[i] = hW[(size_t)s * 64 + l];  // OOB edges: s=0,c=0 -> harmless hot line
      }
#pragma unroll
      for (int i = 0; i < 16; i++) {
        float2 f = __half22float2(v[i]);
        acc.x += f.x * c[i];
        acc.y += f.y * c[i];
      }
    }
  }
  float a = *slope;
  float2 b = *(const float2*)&bias[l * 2];
  acc.x += b.x;
  acc.y += b.y;
  acc.x = acc.x >= 0.f ? acc.x : a * acc.x;
  acc.y = acc.y >= 0.f ? acc.y : a * acc.y;
  if (POOL) {
    int g = batch[wid];
    atomicAdd(&pool[(size_t)g * 128 + l * 2], acc.x);
    atomicAdd(&pool[(size_t)g * 128 + l * 2 + 1], acc.y);
    if (l == 0) atomicAdd(&cntg[g], 1.0f);
  } else {
    outh[(size_t)wid * 64 + l] = __float22half2_rn(acc);
  }
}

// Per-graph: mean, L2-normalize, out = hg @ fc2_w.T + fc2_b.  1 wave/graph.
__global__ __launch_bounds__(64) void k_final(const float* __restrict__ pool,
                                              const float* __restrict__ cntg,
                                              const float* __restrict__ fc2w,
                                              const float* __restrict__ fc2b,
                                              float* __restrict__ out) {
  __shared__ float hg[128];
  int g = blockIdx.x, l = threadIdx.x;
  float cnt = cntg[g];
  float ic = 1.0f / fmaxf(cnt, 1.0f);
  float2 v = *(const float2*)&pool[(size_t)g * 128 + l * 2];
  v.x *= ic;
  v.y *= ic;
  float ss = v.x * v.x + v.y * v.y;
#pragma unroll
  for (int off = 1; off < 64; off <<= 1) ss += __shfl_xor(ss, off);
  float nrm = sqrtf(ss);
  float sc = 1.0f / fmaxf(nrm, 1e-12f);
  hg[l * 2] = v.x * sc;
  hg[l * 2 + 1] = v.y * sc;
  __syncthreads();
  float acc = fc2b[l];
#pragma unroll 4
  for (int k = 0; k < 128; k++) acc += hg[k] * fc2w[l * 128 + k];
  out[(size_t)g * 64 + l] = acc;
}

extern "C" void kernel_launch(void* const* d_in, const int* in_sizes, int n_in,
                              void* d_out, int out_size, void* d_ws, size_t ws_size,
                              hipStream_t stream) {
  const float* x = (const float*)d_in[0];
  const int* ei = (const int*)d_in[1];
  const float* ew = (const float*)d_in[2];
  const int* batch = (const int*)d_in[3];
  const float* fc1_w = (const float*)d_in[4];
  const float* fc1_b = (const float*)d_in[5];
  const float* gc1_w = (const float*)d_in[6];
  const float* gc1_b = (const float*)d_in[7];
  const float* gc2_w = (const float*)d_in[8];
  const float* gc2_b = (const float*)d_in[9];
  const float* fc2_w = (const float*)d_in[10];
  const float* fc2_b = (const float*)d_in[11];
  const float* a_fc1 = (const float*)d_in[12];
  const float* a_gc1 = (const float*)d_in[13];
  const float* a_gc2 = (const float*)d_in[14];

  int N = in_sizes[0] / 128;
  int E = in_sizes[2];
  int G = out_size / 64;
  const int* src = ei;
  const int* dst = ei + E;

  char* p = (char*)d_ws;
  auto carve = [&](size_t bytes) -> char* {
    char* r = p;
    p += (bytes + 255) & ~(size_t)255;
    return r;
  };
  f16* bufA = (f16*)carve((size_t)N * 128 * 2);       // h (fp16 rows)
  f16* bufH = (f16*)carve((size_t)N * 128 * 2);       // hW (fp16 rows)
  int2* csr = (int2*)carve((size_t)E * 8);            // (src, coef-bits)
  int* cnt = (int*)carve((size_t)N * 4);
  int* rowptr = (int*)carve((size_t)(N + 1) * 4);
  int* cursor = (int*)carve((size_t)N * 4);
  float* degf = (float*)carve((size_t)N * 4);
  float* dis = (float*)carve((size_t)N * 4);
  float* inv = (float*)carve((size_t)N * 4);
  f16x8* Bf1 = (f16x8*)carve(2048 * 16);
  f16x8* Bf2 = (f16x8*)carve(2048 * 16);
  f16x8* Bf3 = (f16x8*)carve(2048 * 16);
  int NC = (N + CHK - 1) / CHK;
  int* chunkSum = (int*)carve((size_t)NC * 4);
  int* chunkOff = (int*)carve((size_t)NC * 4);
  float* pool = (float*)carve((size_t)G * 128 * 4);
  float* cntg = (float*)carve((size_t)G * 4);

  hipMemsetAsync(cnt, 0, (size_t)N * 4, stream);
  hipMemsetAsync(degf, 0, (size_t)N * 4, stream);
  hipMemsetAsync(pool, 0, (size_t)G * 128 * 4, stream);
  hipMemsetAsync(cntg, 0, (size_t)G * 4, stream);

  k_prep_bfrag<<<8, 256, 0, stream>>>(fc1_w, Bf1);
  k_prep_bfrag<<<8, 256, 0, stream>>>(gc1_w, Bf2);
  k_prep_bfrag<<<8, 256, 0, stream>>>(gc2_w, Bf3);

  int gE = (E + 255) / 256;
  int gN = (N + 255) / 256;
  k_hist<<<gE, 256, 0, stream>>>(dst, ew, cnt, degf, E);
  k_dis<<<gN, 256, 0, stream>>>(degf, dis, inv, N);
  k_scan_reduce<<<NC, 256, 0, stream>>>(cnt, chunkSum, N);
  k_scan_chunks<<<1, 64, 0, stream>>>(chunkSum, chunkOff, NC);
  k_scan_final<<<NC, 256, 0, stream>>>(cnt, chunkOff, rowptr, cursor, N, E);
  k_scatter<<<gE, 256, 0, stream>>>(src, dst, ew, dis, cursor, csr, E);

  int gGemm = (N + 63) / 64;
  int gAgg = (int)(((size_t)N * 64 + 255) / 256);

  // h1 = prelu(x @ fc1_w.T + fc1_b) -> bufA (fp16)
  k_gemm_mfma<true, true><<<gGemm, 256, 0, stream>>>(nullptr, x, Bf1, bufA, fc1_b, a_fc1, N);
  // conv1: hW = h @ gc1_w.T -> bufH ; aggregate -> bufA
  k_gemm_mfma<false, false><<<gGemm, 256, 0, stream>>>(bufA, nullptr, Bf2, bufH, nullptr, nullptr, N);
  k_agg_h<false><<<gAgg, 256, 0, stream>>>((const __half2*)bufH, rowptr, csr, inv, gc1_b,
                                           a_gc1, batch, (__half2*)bufA, nullptr, cntg, N);
  // conv2: hW = h @ gc2_w.T -> bufH ; aggregate + pool (fused)
  k_gemm_mfma<false, false><<<gGemm, 256, 0, stream>>>(bufA, nullptr, Bf3, bufH, nullptr, nullptr, N);
  k_agg_h<true><<<gAgg, 256, 0, stream>>>((const __half2*)bufH, rowptr, csr, inv, gc2_b,
                                          a_gc2, batch, nullptr, pool, cntg, N);
  k_final<<<G, 64, 0, stream>>>(pool, cntg, fc2_w, fc2_b, (float*)d_out);
}